// Round 1
// baseline (301.088 us; speedup 1.0000x reference)
//
#include <hip/hip_runtime.h>
#include <math.h>

#define Bn 8
#define Ln 8192
#define Dn 768
#define NEn 128
#define NPAIR 8128   // 128*127/2

// ---------------- workspace layout (bytes) ----------------
// emb   : float[B*NE*D]          @ 0            (3,145,728 B)
// norms : float[B*NE]            @ 3,145,728    (4,096 B)
// sim   : float[B*NE*NE]         @ 3,149,824    (524,288 B)
// sums  : double[B*2] (sum,sumsq)@ 3,674,112    (128 B)
#define OFF_NORMS  (Bn*NEn*Dn)
#define OFF_SIM    (OFF_NORMS + Bn*NEn)
#define OFF_SUMS_B ((size_t)(OFF_SIM + Bn*NEn*NEn) * 4)

// Kernel 1: span mean-pool + per-entity L2 norm.
// One block (256 threads) per (b,e); each thread owns 3 of the 768 dims.
__global__ __launch_bounds__(256) void pool_kernel(
    const float* __restrict__ x, const int* __restrict__ starts,
    const int* __restrict__ lengths, float* __restrict__ emb,
    float* __restrict__ norms) {
  int be = blockIdx.x;            // b*NE + e
  int b  = be >> 7;
  int t  = threadIdx.x;
  int s   = starts[be];
  int len = lengths[be];
  const float* base = x + ((size_t)b * Ln + s) * Dn;
  float a0 = 0.f, a1 = 0.f, a2 = 0.f;
  for (int r = 0; r < len; ++r) {
    const float* row = base + (size_t)r * Dn;
    a0 += row[t];
    a1 += row[t + 256];
    a2 += row[t + 512];
  }
  float inv = 1.0f / (float)len;
  a0 *= inv; a1 *= inv; a2 *= inv;
  float* e = emb + (size_t)be * Dn;
  e[t] = a0; e[t + 256] = a1; e[t + 512] = a2;

  // block reduce sum of squares -> norm
  float ss = a0*a0 + a1*a1 + a2*a2;
  for (int off = 32; off; off >>= 1) ss += __shfl_down(ss, off);
  __shared__ float red[4];
  int wave = t >> 6;
  if ((t & 63) == 0) red[wave] = ss;
  __syncthreads();
  if (t == 0) norms[be] = sqrtf(red[0] + red[1] + red[2] + red[3]);
}

// Kernel 2: one block per (b,i) row of the sim matrix. emb_i staged in LDS;
// 4 waves each sweep j in strides of 4, shuffle-reduced dot products.
// Per-block partial sum/sumsq -> one double atomicAdd pair per block.
__global__ __launch_bounds__(256) void sim_kernel(
    const float* __restrict__ emb, const float* __restrict__ norms,
    float* __restrict__ sim, double* __restrict__ sums) {
  int bi = blockIdx.x;            // b*NE + i
  int b  = bi >> 7;
  int t  = threadIdx.x;
  int lane = t & 63;
  int wave = t >> 6;

  __shared__ float ei[Dn];
  __shared__ float wsum[4], wsq[4];
  const float* e_i = emb + (size_t)bi * Dn;
  ei[t] = e_i[t]; ei[t + 256] = e_i[t + 256]; ei[t + 512] = e_i[t + 512];
  __syncthreads();

  float norm_i = norms[bi];
  float lsum = 0.f, lsq = 0.f;
  for (int j = wave; j < NEn; j += 4) {
    const float* e_j = emb + ((size_t)(b * NEn + j)) * Dn;
    float dot = 0.f;
#pragma unroll
    for (int c = 0; c < 12; ++c)
      dot += ei[lane + 64 * c] * e_j[lane + 64 * c];
    for (int off = 32; off; off >>= 1) dot += __shfl_down(dot, off);
    if (lane == 0) {
      float nj  = norms[b * NEn + j];
      float den = fmaxf(norm_i * nj, 1e-8f);
      float v   = dot / den;
      sim[(size_t)bi * NEn + j] = v;
      lsum += v; lsq += v * v;
    }
  }
  if (lane == 0) { wsum[wave] = lsum; wsq[wave] = lsq; }
  __syncthreads();
  if (t == 0) {
    double s = (double)wsum[0] + wsum[1] + wsum[2] + wsum[3];
    double q = (double)wsq[0]  + wsq[1]  + wsq[2]  + wsq[3];
    atomicAdd(&sums[b * 2 + 0], s);
    atomicAdd(&sums[b * 2 + 1], q);
  }
}

// Kernel 3: per-pair standardization + tiny MLP (1->128->2).
__global__ __launch_bounds__(256) void head_kernel(
    const float* __restrict__ sim, const double* __restrict__ sums,
    const int* __restrict__ hts, const float* __restrict__ thr,
    const float* __restrict__ W1, const float* __restrict__ b1,
    const float* __restrict__ W2, const float* __restrict__ b2,
    float* __restrict__ out) {
  __shared__ float sW1[128], sb1[128], sW2[256];
  int t = threadIdx.x;
  if (t < 128) { sW1[t] = W1[t]; sb1[t] = b1[t]; }
  sW2[t] = W2[t];
  __syncthreads();

  int p = blockIdx.x * 256 + t;           // global pair index, exact grid
  int b = p / NPAIR;
  int i = hts[(size_t)p * 2];
  int j = hts[(size_t)p * 2 + 1];

  double ssum = sums[b * 2 + 0];
  double ssq  = sums[b * 2 + 1];
  const double N = (double)(NEn * NEn);
  double var  = (ssq - ssum * ssum / N) / (N - 1.0);
  float stdv  = (float)sqrt(var);

  float v = sim[((size_t)b * NEn + i) * NEn + j];
  float s = (v - thr[0]) / (stdv + 1e-5f);

  float acc0 = b2[0], acc1 = b2[1];
#pragma unroll 8
  for (int k = 0; k < 128; ++k) {
    float h = fmaxf(s * sW1[k] + sb1[k], 0.0f);
    acc0 += h * sW2[2 * k];
    acc1 += h * sW2[2 * k + 1];
  }
  out[(size_t)p * 2]     = acc0;
  out[(size_t)p * 2 + 1] = acc1;
}

extern "C" void kernel_launch(void* const* d_in, const int* in_sizes, int n_in,
                              void* d_out, int out_size, void* d_ws, size_t ws_size,
                              hipStream_t stream) {
  const float* x       = (const float*)d_in[0];
  const int*   starts  = (const int*)d_in[1];
  const int*   lengths = (const int*)d_in[2];
  const int*   hts     = (const int*)d_in[3];
  const float* thr     = (const float*)d_in[4];
  const float* W1      = (const float*)d_in[5];
  const float* b1      = (const float*)d_in[6];
  const float* W2      = (const float*)d_in[7];
  const float* b2      = (const float*)d_in[8];
  float* out = (float*)d_out;

  float*  emb   = (float*)d_ws;
  float*  norms = emb + OFF_NORMS;
  float*  sim   = emb + OFF_SIM;
  double* sums  = (double*)((char*)d_ws + OFF_SUMS_B);

  // zero the double accumulators (ws is poisoned each call)
  hipMemsetAsync(sums, 0, Bn * 2 * sizeof(double), stream);

  pool_kernel<<<Bn * NEn, 256, 0, stream>>>(x, starts, lengths, emb, norms);
  sim_kernel<<<Bn * NEn, 256, 0, stream>>>(emb, norms, sim, sums);
  head_kernel<<<(Bn * NPAIR) / 256, 256, 0, stream>>>(
      sim, sums, hts, thr, W1, b1, W2, b2, out);
}

// Round 2
// 298.036 us; speedup vs baseline: 1.0102x; 1.0102x over previous
//
#include <hip/hip_runtime.h>
#include <math.h>

#define Bn 8
#define Ln 8192
#define Dn 768
#define NEn 128
#define NPAIR 8128   // 128*127/2

// ---------------- workspace layout ----------------
// emb   : float[B*NE*D]          @ 0
// norms : float[B*NE]
// sim   : float[B*NE*NE]
// sums  : double[B*2] (sum,sumsq)
#define OFF_NORMS  (Bn*NEn*Dn)
#define OFF_SIM    (OFF_NORMS + Bn*NEn)
#define OFF_SUMS_B ((size_t)(OFF_SIM + Bn*NEn*NEn) * 4)

// Kernel 1: span mean-pool + per-entity L2 norm, float4 I/O.
// 192 threads (3 waves); thread t owns cols 4t..4t+3 of the 768-dim row.
// Block 0 also zero-inits the double accumulators (ws is poisoned 0xAA).
__global__ __launch_bounds__(192) void pool_kernel(
    const float* __restrict__ x, const int* __restrict__ starts,
    const int* __restrict__ lengths, float* __restrict__ emb,
    float* __restrict__ norms, double* __restrict__ sums) {
  int be = blockIdx.x;            // b*NE + e
  int b  = be >> 7;
  int t  = threadIdx.x;
  if (be == 0 && t < Bn * 2) sums[t] = 0.0;

  int s   = starts[be];
  int len = lengths[be];
  const float4* base = (const float4*)(x + ((size_t)b * Ln + s) * Dn);
  float4 acc = make_float4(0.f, 0.f, 0.f, 0.f);
  for (int r = 0; r < len; ++r) {
    float4 v = base[(size_t)r * 192 + t];
    acc.x += v.x; acc.y += v.y; acc.z += v.z; acc.w += v.w;
  }
  float inv = 1.0f / (float)len;
  acc.x *= inv; acc.y *= inv; acc.z *= inv; acc.w *= inv;
  ((float4*)(emb + (size_t)be * Dn))[t] = acc;

  // block reduce sum of squares -> norm
  float ss = acc.x*acc.x + acc.y*acc.y + acc.z*acc.z + acc.w*acc.w;
  for (int off = 32; off; off >>= 1) ss += __shfl_down(ss, off);
  __shared__ float red[3];
  if ((t & 63) == 0) red[t >> 6] = ss;
  __syncthreads();
  if (t == 0) norms[be] = sqrtf(red[0] + red[1] + red[2]);
}

// Kernel 2: one block per (b,i) row of sim. emb_i staged in LDS as float4;
// 4 waves sweep j in strides of 4; float4 loads of e_j; shuffle-reduced dots.
// Per-block partial sum/sumsq -> one double atomicAdd pair per block.
__global__ __launch_bounds__(256) void sim_kernel(
    const float* __restrict__ emb, const float* __restrict__ norms,
    float* __restrict__ sim, double* __restrict__ sums) {
  int bi = blockIdx.x;            // b*NE + i
  int b  = bi >> 7;
  int t  = threadIdx.x;
  int lane = t & 63;
  int wave = t >> 6;

  __shared__ float4 ei4[192];
  __shared__ float wsum[4], wsq[4];
  const float4* e_i = (const float4*)(emb + (size_t)bi * Dn);
  if (t < 192) ei4[t] = e_i[t];
  __syncthreads();

  float norm_i = norms[bi];
  float lsum = 0.f, lsq = 0.f;
  for (int j = wave; j < NEn; j += 4) {
    const float4* e_j = (const float4*)(emb + ((size_t)(b * NEn + j)) * Dn);
    float dot = 0.f;
#pragma unroll
    for (int c = 0; c < 3; ++c) {
      float4 a = ei4[lane + 64 * c];
      float4 v = e_j[lane + 64 * c];
      dot += a.x*v.x + a.y*v.y + a.z*v.z + a.w*v.w;
    }
    for (int off = 32; off; off >>= 1) dot += __shfl_down(dot, off);
    if (lane == 0) {
      float nj  = norms[b * NEn + j];
      float den = fmaxf(norm_i * nj, 1e-8f);
      float v   = dot / den;
      sim[(size_t)bi * NEn + j] = v;
      lsum += v; lsq += v * v;
    }
  }
  if (lane == 0) { wsum[wave] = lsum; wsq[wave] = lsq; }
  __syncthreads();
  if (t == 0) {
    double s = (double)wsum[0] + wsum[1] + wsum[2] + wsum[3];
    double q = (double)wsq[0]  + wsq[1]  + wsq[2]  + wsq[3];
    atomicAdd(&sums[b * 2 + 0], s);
    atomicAdd(&sums[b * 2 + 1], q);
  }
}

// Kernel 3: per-pair standardization + tiny MLP (1->128->2).
__global__ __launch_bounds__(256) void head_kernel(
    const float* __restrict__ sim, const double* __restrict__ sums,
    const int* __restrict__ hts, const float* __restrict__ thr,
    const float* __restrict__ W1, const float* __restrict__ b1,
    const float* __restrict__ W2, const float* __restrict__ b2,
    float* __restrict__ out) {
  __shared__ float sW1[128], sb1[128], sW2[256];
  int t = threadIdx.x;
  if (t < 128) { sW1[t] = W1[t]; sb1[t] = b1[t]; }
  sW2[t] = W2[t];
  __syncthreads();

  int p = blockIdx.x * 256 + t;           // global pair index, exact grid
  int b = p / NPAIR;
  int i = hts[(size_t)p * 2];
  int j = hts[(size_t)p * 2 + 1];

  double ssum = sums[b * 2 + 0];
  double ssq  = sums[b * 2 + 1];
  const double N = (double)(NEn * NEn);
  double var  = (ssq - ssum * ssum / N) / (N - 1.0);
  float stdv  = (float)sqrt(var);

  float v = sim[((size_t)b * NEn + i) * NEn + j];
  float s = (v - thr[0]) / (stdv + 1e-5f);

  float acc0 = b2[0], acc1 = b2[1];
#pragma unroll 8
  for (int k = 0; k < 128; ++k) {
    float h = fmaxf(s * sW1[k] + sb1[k], 0.0f);
    acc0 += h * sW2[2 * k];
    acc1 += h * sW2[2 * k + 1];
  }
  ((float2*)out)[p] = make_float2(acc0, acc1);
}

extern "C" void kernel_launch(void* const* d_in, const int* in_sizes, int n_in,
                              void* d_out, int out_size, void* d_ws, size_t ws_size,
                              hipStream_t stream) {
  const float* x       = (const float*)d_in[0];
  const int*   starts  = (const int*)d_in[1];
  const int*   lengths = (const int*)d_in[2];
  const int*   hts     = (const int*)d_in[3];
  const float* thr     = (const float*)d_in[4];
  const float* W1      = (const float*)d_in[5];
  const float* b1      = (const float*)d_in[6];
  const float* W2      = (const float*)d_in[7];
  const float* b2      = (const float*)d_in[8];
  float* out = (float*)d_out;

  float*  emb   = (float*)d_ws;
  float*  norms = emb + OFF_NORMS;
  float*  sim   = emb + OFF_SIM;
  double* sums  = (double*)((char*)d_ws + OFF_SUMS_B);

  pool_kernel<<<Bn * NEn, 192, 0, stream>>>(x, starts, lengths, emb, norms, sums);
  sim_kernel<<<Bn * NEn, 256, 0, stream>>>(emb, norms, sim, sums);
  head_kernel<<<(Bn * NPAIR) / 256, 256, 0, stream>>>(
      sim, sums, hts, thr, W1, b1, W2, b2, out);
}

// Round 3
// 269.847 us; speedup vs baseline: 1.1158x; 1.1045x over previous
//
#include <hip/hip_runtime.h>
#include <math.h>

#define Bn 8
#define Ln 8192
#define Dn 768
#define NEn 128
#define NPAIR 8128   // 128*127/2

// ---------------- workspace layout ----------------
#define OFF_NORMS  (Bn*NEn*Dn)
#define OFF_SIM    (OFF_NORMS + Bn*NEn)
#define OFF_SUMS_B ((size_t)(OFF_SIM + Bn*NEn*NEn) * 4)

// Kernel 1: span mean-pool + per-entity L2 norm, float4 I/O.
// 192 threads; thread t owns cols 4t..4t+3. Block 0 zeros the double sums.
__global__ __launch_bounds__(192) void pool_kernel(
    const float* __restrict__ x, const int* __restrict__ starts,
    const int* __restrict__ lengths, float* __restrict__ emb,
    float* __restrict__ norms, double* __restrict__ sums) {
  int be = blockIdx.x;            // b*NE + e
  int b  = be >> 7;
  int t  = threadIdx.x;
  if (be == 0 && t < Bn * 2) sums[t] = 0.0;

  int s   = starts[be];
  int len = lengths[be];
  const float4* base = (const float4*)(x + ((size_t)b * Ln + s) * Dn);
  float4 acc = make_float4(0.f, 0.f, 0.f, 0.f);
  for (int r = 0; r < len; ++r) {
    float4 v = base[(size_t)r * 192 + t];
    acc.x += v.x; acc.y += v.y; acc.z += v.z; acc.w += v.w;
  }
  float inv = 1.0f / (float)len;
  acc.x *= inv; acc.y *= inv; acc.z *= inv; acc.w *= inv;
  ((float4*)(emb + (size_t)be * Dn))[t] = acc;

  float ss = acc.x*acc.x + acc.y*acc.y + acc.z*acc.z + acc.w*acc.w;
  for (int off = 32; off; off >>= 1) ss += __shfl_down(ss, off);
  __shared__ float red[3];
  if ((t & 63) == 0) red[t >> 6] = ss;
  __syncthreads();
  if (t == 0) norms[be] = sqrtf(red[0] + red[1] + red[2]);
}

// Kernel 2 (register-tiled): grid = 256 blocks; block = (b, 4 i-rows).
// 4 i-rows staged in LDS as float4 with padded stride 193 (sub-lanes hit
// distinct bank quads). Wave covers 32 j; lane group g (16 groups of 4)
// owns j = wave*32 + 2g + {0,1}; the 4 sub-lanes split the 768-dim dot
// (48 float4 chunks each). Per k-step: 2 global f4 + 4 ds_read_b128 +
// 32 v_fma -> FMA-bound. Group-reduce = 2 shfl per 8 dots.
__global__ __launch_bounds__(256) void sim_kernel(
    const float* __restrict__ emb, const float* __restrict__ norms,
    float* __restrict__ sim, double* __restrict__ sums) {
  int blk = blockIdx.x;
  int b   = blk >> 5;
  int i0  = (blk & 31) * 4;
  int t    = threadIdx.x;
  int lane = t & 63;
  int wave = t >> 6;
  int g    = lane >> 2;           // 0..15 : j-group
  int l    = lane & 3;            // 0..3  : dim-split sub-lane

  __shared__ float4 ei4[4 * 193];
  __shared__ float wsum[4], wsq[4];

  const float4* embf4 = (const float4*)emb;
  for (int idx = t; idx < 4 * 192; idx += 256) {
    int r = idx / 192, c = idx - r * 192;
    ei4[r * 193 + c] = embf4[(size_t)(b * NEn + i0 + r) * 192 + c];
  }
  __syncthreads();

  int j0 = wave * 32 + g * 2;
  const float4* ej0 = embf4 + (size_t)(b * NEn + j0) * 192;
  const float4* ej1 = ej0 + 192;

  float acc00=0.f, acc01=0.f, acc10=0.f, acc11=0.f;
  float acc20=0.f, acc21=0.f, acc30=0.f, acc31=0.f;
#pragma unroll 4
  for (int k = 0; k < 48; ++k) {
    float4 e0 = ej0[4 * k + l];
    float4 e1 = ej1[4 * k + l];
    float4 a0 = ei4[0 * 193 + 4 * k + l];
    float4 a1 = ei4[1 * 193 + 4 * k + l];
    float4 a2 = ei4[2 * 193 + 4 * k + l];
    float4 a3 = ei4[3 * 193 + 4 * k + l];
    acc00 += a0.x*e0.x + a0.y*e0.y + a0.z*e0.z + a0.w*e0.w;
    acc01 += a0.x*e1.x + a0.y*e1.y + a0.z*e1.z + a0.w*e1.w;
    acc10 += a1.x*e0.x + a1.y*e0.y + a1.z*e0.z + a1.w*e0.w;
    acc11 += a1.x*e1.x + a1.y*e1.y + a1.z*e1.z + a1.w*e1.w;
    acc20 += a2.x*e0.x + a2.y*e0.y + a2.z*e0.z + a2.w*e0.w;
    acc21 += a2.x*e1.x + a2.y*e1.y + a2.z*e1.z + a2.w*e1.w;
    acc30 += a3.x*e0.x + a3.y*e0.y + a3.z*e0.z + a3.w*e0.w;
    acc31 += a3.x*e1.x + a3.y*e1.y + a3.z*e1.z + a3.w*e1.w;
  }
  // reduce each acc over the 4 sub-lanes (result lands in l==0)
#define RED(v) v += __shfl_down(v, 1); v += __shfl_down(v, 2);
  RED(acc00) RED(acc01) RED(acc10) RED(acc11)
  RED(acc20) RED(acc21) RED(acc30) RED(acc31)
#undef RED

  float lsum = 0.f, lsq = 0.f;
  if (l == 0) {
    float nj0 = norms[b * NEn + j0];
    float nj1 = norms[b * NEn + j0 + 1];
    float dots[4][2] = {{acc00,acc01},{acc10,acc11},{acc20,acc21},{acc30,acc31}};
#pragma unroll
    for (int i = 0; i < 4; ++i) {
      float ni = norms[b * NEn + i0 + i];
      float v0 = dots[i][0] / fmaxf(ni * nj0, 1e-8f);
      float v1 = dots[i][1] / fmaxf(ni * nj1, 1e-8f);
      float* row = sim + ((size_t)(b * NEn + i0 + i)) * NEn + j0;
      row[0] = v0; row[1] = v1;
      lsum += v0 + v1; lsq += v0*v0 + v1*v1;
    }
  }
  // full-wave binary reduce (non-l0 lanes contribute zeros)
  for (int off = 32; off; off >>= 1) {
    lsum += __shfl_down(lsum, off);
    lsq  += __shfl_down(lsq,  off);
  }
  if (lane == 0) { wsum[wave] = lsum; wsq[wave] = lsq; }
  __syncthreads();
  if (t == 0) {
    double s = (double)wsum[0] + wsum[1] + wsum[2] + wsum[3];
    double q = (double)wsq[0]  + wsq[1]  + wsq[2]  + wsq[3];
    atomicAdd(&sums[b * 2 + 0], s);
    atomicAdd(&sums[b * 2 + 1], q);
  }
}

// Kernel 3: per-pair standardization + tiny MLP (1->128->2).
__global__ __launch_bounds__(256) void head_kernel(
    const float* __restrict__ sim, const double* __restrict__ sums,
    const int* __restrict__ hts, const float* __restrict__ thr,
    const float* __restrict__ W1, const float* __restrict__ b1,
    const float* __restrict__ W2, const float* __restrict__ b2,
    float* __restrict__ out) {
  __shared__ float sW1[128], sb1[128], sW2[256];
  int t = threadIdx.x;
  if (t < 128) { sW1[t] = W1[t]; sb1[t] = b1[t]; }
  sW2[t] = W2[t];
  __syncthreads();

  int p = blockIdx.x * 256 + t;           // exact grid
  int b = p / NPAIR;
  int i = hts[(size_t)p * 2];
  int j = hts[(size_t)p * 2 + 1];

  double ssum = sums[b * 2 + 0];
  double ssq  = sums[b * 2 + 1];
  const double N = (double)(NEn * NEn);
  double var  = (ssq - ssum * ssum / N) / (N - 1.0);
  float stdv  = (float)sqrt(var);

  float v = sim[((size_t)b * NEn + i) * NEn + j];
  float s = (v - thr[0]) / (stdv + 1e-5f);

  float acc0 = b2[0], acc1 = b2[1];
#pragma unroll 8
  for (int k = 0; k < 128; ++k) {
    float h = fmaxf(s * sW1[k] + sb1[k], 0.0f);
    acc0 += h * sW2[2 * k];
    acc1 += h * sW2[2 * k + 1];
  }
  ((float2*)out)[p] = make_float2(acc0, acc1);
}

extern "C" void kernel_launch(void* const* d_in, const int* in_sizes, int n_in,
                              void* d_out, int out_size, void* d_ws, size_t ws_size,
                              hipStream_t stream) {
  const float* x       = (const float*)d_in[0];
  const int*   starts  = (const int*)d_in[1];
  const int*   lengths = (const int*)d_in[2];
  const int*   hts     = (const int*)d_in[3];
  const float* thr     = (const float*)d_in[4];
  const float* W1      = (const float*)d_in[5];
  const float* b1      = (const float*)d_in[6];
  const float* W2      = (const float*)d_in[7];
  const float* b2      = (const float*)d_in[8];
  float* out = (float*)d_out;

  float*  emb   = (float*)d_ws;
  float*  norms = emb + OFF_NORMS;
  float*  sim   = emb + OFF_SIM;
  double* sums  = (double*)((char*)d_ws + OFF_SUMS_B);

  pool_kernel<<<Bn * NEn, 192, 0, stream>>>(x, starts, lengths, emb, norms, sums);
  sim_kernel<<<Bn * 32, 256, 0, stream>>>(emb, norms, sim, sums);
  head_kernel<<<(Bn * NPAIR) / 256, 256, 0, stream>>>(
      sim, sums, hts, thr, W1, b1, W2, b2, out);
}